// Round 9
// baseline (122.923 us; speedup 1.0000x reference)
//
#include <hip/hip_runtime.h>
#include <hip/hip_bf16.h>

// Bloom MLP fused: h=X@W1^T+b1; g=gelu_tanh(h); out=g@W2^T+b2+residual
// X:[262144,64] f32, W1:[256,64], W2:[64,256], out:[262144,64] f32.
//
// Round 9: TLP push. 8-wave (512-thread) blocks over the SAME 64-token /
// 33.8KB Gs tile -> double the waves per LDS byte (r4/r8 were 4-wave and
// capped at 12-16 waves/CU; barriers+serial phases left SIMDs empty).
// TILES=1: block = GEMM1 -> one __syncthreads -> GEMM2 -> done.
//  - GEMM1: wave w owns 32-f slice (w1f 2x2 frags), 16 MFMA, 32 gelu/lane.
//  - GEMM2: wave w owns (d-tile w&3, token-half w>>2), 16 MFMA, 4 acc chains.
//  - launch_bounds(512,4): VGPR cap 128, est ~75 -> no spills (r5 lesson),
//    natural usage <=85 still allows 3 blocks = 24 waves = 75%.
// grid 4096 x 64 tokens.

typedef __attribute__((ext_vector_type(8))) short bf16x8;   // MFMA A/B frag
typedef __attribute__((ext_vector_type(4))) float f32x4;    // MFMA C/D frag
typedef __attribute__((ext_vector_type(4))) short short4v;  // packed 4x bf16

#define NBLK 4096    // 4096 blocks * 64 tokens = 262144

__device__ __forceinline__ short f2bf(float x) {
    union { __hip_bfloat16 h; short s; } u;
    u.h = __float2bfloat16(x);      // compiler pairs into v_cvt_pk_bf16_f32
    return u.s;
}

__device__ __forceinline__ float bloom_gelu(float x) {
    // 0.5*x*(1+tanh(0.79788456*(x+0.044715*x^3))) = x*(1 - 1/(e^{2u}+1))
    // 2u*log2(e) = 2.30220842*x + 0.10294325*x^3 -> v_exp_f32 (2^x) direct
    float x2 = x * x;
    float t1 = __builtin_fmaf(0.10294325f, x2, 2.30220842f);
    float e  = __builtin_exp2f(x * t1);
    float r  = __builtin_amdgcn_rcpf(e + 1.0f);
    return x - x * r;
}

// ---- pre-pass: convert W1 (16384 f32) then W2 (16384 f32) to bf16 in ws ----
__global__ __launch_bounds__(256) void cvt_weights(
    const float* __restrict__ W1, const float* __restrict__ W2,
    short* __restrict__ wsb)
{
    const int i4 = (blockIdx.x * 256 + threadIdx.x) * 4;   // 0..32764, step 4
    const float* src = (i4 < 16384) ? (W1 + i4) : (W2 + (i4 - 16384));
    float4 v = *(const float4*)src;
    short4v o;
    o[0] = f2bf(v.x); o[1] = f2bf(v.y); o[2] = f2bf(v.z); o[3] = f2bf(v.w);
    *(short4v*)(wsb + i4) = o;
}

template<bool PRE>
__global__ __launch_bounds__(512, 4) void bloom_mlp(
    const float* __restrict__ X,  const float* __restrict__ R,
    const float* __restrict__ W1, const float* __restrict__ b1,
    const float* __restrict__ W2, const float* __restrict__ b2,
    const short* __restrict__ Wb, float* __restrict__ out)
{
    // G[token][f] bf16, 64 tokens, row stride 264 (528B): ds_write_b64 at
    // 2 acc/bank (free), ds_read_b128 at 8 acc/bank -- the width minimum.
    __shared__ __align__(16) short Gs[64][264];   // 33792 B

    const int tid  = threadIdx.x;
    const int wid  = tid >> 6;      // wave 0..7
    const int lane = tid & 63;
    const int q    = lane >> 4;     // 0..3
    const int c    = lane & 15;     // 0..15
    const int f0   = wid << 5;      // GEMM1 f-slice base (32 f per wave)
    const int dt   = wid & 3;       // GEMM2 d-tile
    const int h    = wid >> 2;      // GEMM2 token half
    const int row0 = blockIdx.x << 6;

    // ---- GEMM1 weights: lane holds W1[f0+16t+c][kb*32+q*8..+7] ----
    bf16x8 w1f[2][2];
    if constexpr (PRE) {
        const short* W1b = Wb;
#pragma unroll
        for (int t = 0; t < 2; ++t)
#pragma unroll
            for (int kb = 0; kb < 2; ++kb)
                w1f[t][kb] = *(const bf16x8*)&W1b[(f0 + 16*t + c) * 64 + kb*32 + q*8];
    } else {
#pragma unroll
        for (int t = 0; t < 2; ++t)
#pragma unroll
            for (int kb = 0; kb < 2; ++kb) {
                const float* p = W1 + (size_t)(f0 + 16*t + c) * 64 + kb*32 + q*8;
                float4 lo = *(const float4*)p, hi = *(const float4*)(p + 4);
                bf16x8 f;
                f[0]=f2bf(lo.x); f[1]=f2bf(lo.y); f[2]=f2bf(lo.z); f[3]=f2bf(lo.w);
                f[4]=f2bf(hi.x); f[5]=f2bf(hi.y); f[6]=f2bf(hi.z); f[7]=f2bf(hi.w);
                w1f[t][kb] = f;
            }
    }
    float4 b1q[2];
#pragma unroll
    for (int t = 0; t < 2; ++t)
        b1q[t] = *(const float4*)(b1 + f0 + 16*t + 4*q);

    // ---- GEMM1 + GELU -> Gs ----
#pragma unroll
    for (int m = 0; m < 4; ++m) {
        bf16x8 a1[2];   // B-op: lane holds X[row0+16m+c][kb*32+q*8..+7]
#pragma unroll
        for (int kb = 0; kb < 2; ++kb) {
            const float* p = X + (size_t)(row0 + 16*m + c) * 64 + kb*32 + q*8;
            float4 lo = *(const float4*)p, hi = *(const float4*)(p + 4);
            bf16x8 f;
            f[0]=f2bf(lo.x); f[1]=f2bf(lo.y); f[2]=f2bf(lo.z); f[3]=f2bf(lo.w);
            f[4]=f2bf(hi.x); f[5]=f2bf(hi.y); f[6]=f2bf(hi.z); f[7]=f2bf(hi.w);
            a1[kb] = f;
        }
        // D[f_local=4q+r][token=c] per f-tile t (W1 as A, X^T as B)
#pragma unroll
        for (int t = 0; t < 2; ++t) {
            f32x4 acc = {0.f, 0.f, 0.f, 0.f};
            acc = __builtin_amdgcn_mfma_f32_16x16x32_bf16(w1f[t][0], a1[0], acc, 0, 0, 0);
            acc = __builtin_amdgcn_mfma_f32_16x16x32_bf16(w1f[t][1], a1[1], acc, 0, 0, 0);
            short4v g;
#pragma unroll
            for (int r = 0; r < 4; ++r)
                g[r] = f2bf(bloom_gelu(acc[r] + b1q[t][r]));
            *(short4v*)&Gs[16*m + c][f0 + 16*t + 4*q] = g;   // 8B packed
        }
    }

    // ---- GEMM2 weights issued pre-barrier (land during the sync):
    //      lane holds W2[16dt+c][kb*32+q*8..+7] ----
    bf16x8 w2f[8];
    if constexpr (PRE) {
        const short* W2b = Wb + 16384;
#pragma unroll
        for (int kb = 0; kb < 8; ++kb)
            w2f[kb] = *(const bf16x8*)&W2b[(16*dt + c) * 256 + kb*32 + q*8];
    } else {
#pragma unroll
        for (int kb = 0; kb < 8; ++kb) {
            const float* p = W2 + (size_t)(16*dt + c) * 256 + kb*32 + q*8;
            float4 lo = *(const float4*)p, hi = *(const float4*)(p + 4);
            bf16x8 f;
            f[0]=f2bf(lo.x); f[1]=f2bf(lo.y); f[2]=f2bf(lo.z); f[3]=f2bf(lo.w);
            f[4]=f2bf(hi.x); f[5]=f2bf(hi.y); f[6]=f2bf(hi.z); f[7]=f2bf(hi.w);
            w2f[kb] = f;
        }
    }

    __syncthreads();   // Gs fully written -> readable by all waves

    // ---- GEMM2: wave owns d-tile [16dt,16dt+16) x tokens [32h,32h+32) ----
    // R issued first: lands under the MFMA chains.
    float4 r4[2];
    const float4 b2q = *(const float4*)(b2 + 16*dt + 4*q);
#pragma unroll
    for (int mi = 0; mi < 2; ++mi)
        r4[mi] = *(const float4*)(R + (size_t)(row0 + 16*(2*h + mi) + c) * 64 + 16*dt + 4*q);

    // D[d_local=4q+r][token=c]; 4 independent chains (2 mi x A/B)
    f32x4 aA[2] = {{0.f,0.f,0.f,0.f},{0.f,0.f,0.f,0.f}};
    f32x4 aB[2] = {{0.f,0.f,0.f,0.f},{0.f,0.f,0.f,0.f}};
#pragma unroll
    for (int kb = 0; kb < 4; ++kb)
#pragma unroll
        for (int mi = 0; mi < 2; ++mi) {
            bf16x8 ga = *(const bf16x8*)&Gs[16*(2*h + mi) + c][kb*32 + q*8];
            aA[mi] = __builtin_amdgcn_mfma_f32_16x16x32_bf16(w2f[kb], ga, aA[mi], 0, 0, 0);
        }
#pragma unroll
    for (int kb = 4; kb < 8; ++kb)
#pragma unroll
        for (int mi = 0; mi < 2; ++mi) {
            bf16x8 ga = *(const bf16x8*)&Gs[16*(2*h + mi) + c][kb*32 + q*8];
            aB[mi] = __builtin_amdgcn_mfma_f32_16x16x32_bf16(w2f[kb], ga, aB[mi], 0, 0, 0);
        }

    // ---- epilogue: float4 out[row0+16m+c][16dt+4q..+3] ----
#pragma unroll
    for (int mi = 0; mi < 2; ++mi) {
        const size_t off = (size_t)(row0 + 16*(2*h + mi) + c) * 64 + 16*dt + 4*q;
        float4 o;
        o.x = aA[mi][0] + aB[mi][0] + b2q.x + r4[mi].x;
        o.y = aA[mi][1] + aB[mi][1] + b2q.y + r4[mi].y;
        o.z = aA[mi][2] + aB[mi][2] + b2q.z + r4[mi].z;
        o.w = aA[mi][3] + aB[mi][3] + b2q.w + r4[mi].w;
        *(float4*)(out + off) = o;
    }
}

extern "C" void kernel_launch(void* const* d_in, const int* in_sizes, int n_in,
                              void* d_out, int out_size, void* d_ws, size_t ws_size,
                              hipStream_t stream) {
    const float* X  = (const float*)d_in[0];
    const float* R  = (const float*)d_in[1];
    const float* W1 = (const float*)d_in[2];
    const float* b1 = (const float*)d_in[3];
    const float* W2 = (const float*)d_in[4];
    const float* b2 = (const float*)d_in[5];
    float* out = (float*)d_out;
    (void)in_sizes; (void)n_in; (void)out_size;

    if (ws_size >= 65536) {
        short* wsb = (short*)d_ws;
        cvt_weights<<<32, 256, 0, stream>>>(W1, W2, wsb);
        bloom_mlp<true><<<NBLK, 512, 0, stream>>>(X, R, W1, b1, W2, b2, wsb, out);
    } else {
        bloom_mlp<false><<<NBLK, 512, 0, stream>>>(X, R, W1, b1, W2, b2, nullptr, out);
    }
}

// Round 10
// 122.404 us; speedup vs baseline: 1.0042x; 1.0042x over previous
//
#include <hip/hip_runtime.h>
#include <hip/hip_bf16.h>

// Bloom MLP fused: h=X@W1^T+b1; g=gelu_tanh(h); out=g@W2^T+b2+residual
// X:[262144,64] f32, W1:[256,64], W2:[64,256], out:[262144,64] f32.
//
// Round 10 = round 9 with ONE change: __launch_bounds__(512) (no min-waves).
// r9's (512,4) strangled the allocator to 32 VGPR -> w2f reloaded from
// global inside the MFMA loop -> 129us at 82% occupancy. r5's (256,6) did
// the same via spills. Natural allocation (~64-88 VGPR) keeps weights
// register-resident; at <=64 VGPR the HW can still reach 8 waves/SIMD,
// LDS 33.8KB allows 4 blocks/CU x 8 waves.
// Structure: 8-wave blocks, 64 tokens, TILES=1, ONE __syncthreads.
//  - GEMM1: wave w owns 32-f slice (w1f 2x2 frags), 16 MFMA, 32 gelu/lane.
//  - GEMM2: wave w owns (d-tile w&3, token-half w>>2), 16 MFMA, 4 acc chains.

typedef __attribute__((ext_vector_type(8))) short bf16x8;   // MFMA A/B frag
typedef __attribute__((ext_vector_type(4))) float f32x4;    // MFMA C/D frag
typedef __attribute__((ext_vector_type(4))) short short4v;  // packed 4x bf16

#define NBLK 4096    // 4096 blocks * 64 tokens = 262144

__device__ __forceinline__ short f2bf(float x) {
    union { __hip_bfloat16 h; short s; } u;
    u.h = __float2bfloat16(x);      // compiler pairs into v_cvt_pk_bf16_f32
    return u.s;
}

__device__ __forceinline__ float bloom_gelu(float x) {
    // 0.5*x*(1+tanh(0.79788456*(x+0.044715*x^3))) = x*(1 - 1/(e^{2u}+1))
    // 2u*log2(e) = 2.30220842*x + 0.10294325*x^3 -> v_exp_f32 (2^x) direct
    float x2 = x * x;
    float t1 = __builtin_fmaf(0.10294325f, x2, 2.30220842f);
    float e  = __builtin_exp2f(x * t1);
    float r  = __builtin_amdgcn_rcpf(e + 1.0f);
    return x - x * r;
}

// ---- pre-pass: convert W1 (16384 f32) then W2 (16384 f32) to bf16 in ws ----
__global__ __launch_bounds__(256) void cvt_weights(
    const float* __restrict__ W1, const float* __restrict__ W2,
    short* __restrict__ wsb)
{
    const int i4 = (blockIdx.x * 256 + threadIdx.x) * 4;   // 0..32764, step 4
    const float* src = (i4 < 16384) ? (W1 + i4) : (W2 + (i4 - 16384));
    float4 v = *(const float4*)src;
    short4v o;
    o[0] = f2bf(v.x); o[1] = f2bf(v.y); o[2] = f2bf(v.z); o[3] = f2bf(v.w);
    *(short4v*)(wsb + i4) = o;
}

template<bool PRE>
__global__ __launch_bounds__(512) void bloom_mlp(
    const float* __restrict__ X,  const float* __restrict__ R,
    const float* __restrict__ W1, const float* __restrict__ b1,
    const float* __restrict__ W2, const float* __restrict__ b2,
    const short* __restrict__ Wb, float* __restrict__ out)
{
    // G[token][f] bf16, 64 tokens, row stride 264 (528B): ds_write_b64 at
    // 2 acc/bank (free), ds_read_b128 at 8 acc/bank -- the width minimum.
    __shared__ __align__(16) short Gs[64][264];   // 33792 B

    const int tid  = threadIdx.x;
    const int wid  = tid >> 6;      // wave 0..7
    const int lane = tid & 63;
    const int q    = lane >> 4;     // 0..3
    const int c    = lane & 15;     // 0..15
    const int f0   = wid << 5;      // GEMM1 f-slice base (32 f per wave)
    const int dt   = wid & 3;       // GEMM2 d-tile
    const int h    = wid >> 2;      // GEMM2 token half
    const int row0 = blockIdx.x << 6;

    // ---- GEMM1 weights: lane holds W1[f0+16t+c][kb*32+q*8..+7] ----
    bf16x8 w1f[2][2];
    if constexpr (PRE) {
        const short* W1b = Wb;
#pragma unroll
        for (int t = 0; t < 2; ++t)
#pragma unroll
            for (int kb = 0; kb < 2; ++kb)
                w1f[t][kb] = *(const bf16x8*)&W1b[(f0 + 16*t + c) * 64 + kb*32 + q*8];
    } else {
#pragma unroll
        for (int t = 0; t < 2; ++t)
#pragma unroll
            for (int kb = 0; kb < 2; ++kb) {
                const float* p = W1 + (size_t)(f0 + 16*t + c) * 64 + kb*32 + q*8;
                float4 lo = *(const float4*)p, hi = *(const float4*)(p + 4);
                bf16x8 f;
                f[0]=f2bf(lo.x); f[1]=f2bf(lo.y); f[2]=f2bf(lo.z); f[3]=f2bf(lo.w);
                f[4]=f2bf(hi.x); f[5]=f2bf(hi.y); f[6]=f2bf(hi.z); f[7]=f2bf(hi.w);
                w1f[t][kb] = f;
            }
    }
    float4 b1q[2];
#pragma unroll
    for (int t = 0; t < 2; ++t)
        b1q[t] = *(const float4*)(b1 + f0 + 16*t + 4*q);

    // ---- GEMM1 + GELU -> Gs ----
#pragma unroll
    for (int m = 0; m < 4; ++m) {
        bf16x8 a1[2];   // B-op: lane holds X[row0+16m+c][kb*32+q*8..+7]
#pragma unroll
        for (int kb = 0; kb < 2; ++kb) {
            const float* p = X + (size_t)(row0 + 16*m + c) * 64 + kb*32 + q*8;
            float4 lo = *(const float4*)p, hi = *(const float4*)(p + 4);
            bf16x8 f;
            f[0]=f2bf(lo.x); f[1]=f2bf(lo.y); f[2]=f2bf(lo.z); f[3]=f2bf(lo.w);
            f[4]=f2bf(hi.x); f[5]=f2bf(hi.y); f[6]=f2bf(hi.z); f[7]=f2bf(hi.w);
            a1[kb] = f;
        }
        // D[f_local=4q+r][token=c] per f-tile t (W1 as A, X^T as B)
#pragma unroll
        for (int t = 0; t < 2; ++t) {
            f32x4 acc = {0.f, 0.f, 0.f, 0.f};
            acc = __builtin_amdgcn_mfma_f32_16x16x32_bf16(w1f[t][0], a1[0], acc, 0, 0, 0);
            acc = __builtin_amdgcn_mfma_f32_16x16x32_bf16(w1f[t][1], a1[1], acc, 0, 0, 0);
            short4v g;
#pragma unroll
            for (int r = 0; r < 4; ++r)
                g[r] = f2bf(bloom_gelu(acc[r] + b1q[t][r]));
            *(short4v*)&Gs[16*m + c][f0 + 16*t + 4*q] = g;   // 8B packed
        }
    }

    // ---- GEMM2 weights issued pre-barrier (land during the sync):
    //      lane holds W2[16dt+c][kb*32+q*8..+7] ----
    bf16x8 w2f[8];
    if constexpr (PRE) {
        const short* W2b = Wb + 16384;
#pragma unroll
        for (int kb = 0; kb < 8; ++kb)
            w2f[kb] = *(const bf16x8*)&W2b[(16*dt + c) * 256 + kb*32 + q*8];
    } else {
#pragma unroll
        for (int kb = 0; kb < 8; ++kb) {
            const float* p = W2 + (size_t)(16*dt + c) * 256 + kb*32 + q*8;
            float4 lo = *(const float4*)p, hi = *(const float4*)(p + 4);
            bf16x8 f;
            f[0]=f2bf(lo.x); f[1]=f2bf(lo.y); f[2]=f2bf(lo.z); f[3]=f2bf(lo.w);
            f[4]=f2bf(hi.x); f[5]=f2bf(hi.y); f[6]=f2bf(hi.z); f[7]=f2bf(hi.w);
            w2f[kb] = f;
        }
    }

    __syncthreads();   // Gs fully written -> readable by all waves

    // ---- GEMM2: wave owns d-tile [16dt,16dt+16) x tokens [32h,32h+32) ----
    // R issued first: lands under the MFMA chains.
    float4 r4[2];
    const float4 b2q = *(const float4*)(b2 + 16*dt + 4*q);
#pragma unroll
    for (int mi = 0; mi < 2; ++mi)
        r4[mi] = *(const float4*)(R + (size_t)(row0 + 16*(2*h + mi) + c) * 64 + 16*dt + 4*q);

    // D[d_local=4q+r][token=c]; 4 independent chains (2 mi x A/B)
    f32x4 aA[2] = {{0.f,0.f,0.f,0.f},{0.f,0.f,0.f,0.f}};
    f32x4 aB[2] = {{0.f,0.f,0.f,0.f},{0.f,0.f,0.f,0.f}};
#pragma unroll
    for (int kb = 0; kb < 4; ++kb)
#pragma unroll
        for (int mi = 0; mi < 2; ++mi) {
            bf16x8 ga = *(const bf16x8*)&Gs[16*(2*h + mi) + c][kb*32 + q*8];
            aA[mi] = __builtin_amdgcn_mfma_f32_16x16x32_bf16(w2f[kb], ga, aA[mi], 0, 0, 0);
        }
#pragma unroll
    for (int kb = 4; kb < 8; ++kb)
#pragma unroll
        for (int mi = 0; mi < 2; ++mi) {
            bf16x8 ga = *(const bf16x8*)&Gs[16*(2*h + mi) + c][kb*32 + q*8];
            aB[mi] = __builtin_amdgcn_mfma_f32_16x16x32_bf16(w2f[kb], ga, aB[mi], 0, 0, 0);
        }

    // ---- epilogue: float4 out[row0+16m+c][16dt+4q..+3] ----
#pragma unroll
    for (int mi = 0; mi < 2; ++mi) {
        const size_t off = (size_t)(row0 + 16*(2*h + mi) + c) * 64 + 16*dt + 4*q;
        float4 o;
        o.x = aA[mi][0] + aB[mi][0] + b2q.x + r4[mi].x;
        o.y = aA[mi][1] + aB[mi][1] + b2q.y + r4[mi].y;
        o.z = aA[mi][2] + aB[mi][2] + b2q.z + r4[mi].z;
        o.w = aA[mi][3] + aB[mi][3] + b2q.w + r4[mi].w;
        *(float4*)(out + off) = o;
    }
}

extern "C" void kernel_launch(void* const* d_in, const int* in_sizes, int n_in,
                              void* d_out, int out_size, void* d_ws, size_t ws_size,
                              hipStream_t stream) {
    const float* X  = (const float*)d_in[0];
    const float* R  = (const float*)d_in[1];
    const float* W1 = (const float*)d_in[2];
    const float* b1 = (const float*)d_in[3];
    const float* W2 = (const float*)d_in[4];
    const float* b2 = (const float*)d_in[5];
    float* out = (float*)d_out;
    (void)in_sizes; (void)n_in; (void)out_size;

    if (ws_size >= 65536) {
        short* wsb = (short*)d_ws;
        cvt_weights<<<32, 256, 0, stream>>>(W1, W2, wsb);
        bloom_mlp<true><<<NBLK, 512, 0, stream>>>(X, R, W1, b1, W2, b2, wsb, out);
    } else {
        bloom_mlp<false><<<NBLK, 512, 0, stream>>>(X, R, W1, b1, W2, b2, nullptr, out);
    }
}

// Round 11
// 92.119 us; speedup vs baseline: 1.3344x; 1.3288x over previous
//
#include <hip/hip_runtime.h>
#include <hip/hip_bf16.h>

// Bloom MLP fused: h=X@W1^T+b1; g=gelu_tanh(h); out=g@W2^T+b2+residual
// X:[262144,64] f32, W1:[256,64], W2:[64,256], out:[262144,64] f32.
//
// Round 11: wave-private everything. NO LDS, NO barriers.
// Trick: GEMM1 (swapped ops) leaves lane(c,q) with G[token=c][f=16t+4q+r].
// MFMA's k-dim can be permuted if BOTH operands agree, so store W2 with
// columns permuted by kappa(f) = [t>>1 | q | t&1 | r] (bijection). Then
// GEMM2's A/B fragment for k-block kb is exactly the concatenation of
// GEMM1 outputs t=2kb,2kb+1 -- a register re-labeling, no data movement.
// One wave owns 32 tokens end-to-end; weights streamed from L1/L2.
//   GEMM1: 16 t x 2 kb x 2 m = 64 MFMA;  GEMM2: 8 kb x 4 dt x 2 m = 64 MFMA.
// 2048 blocks x 256 thr (4 independent waves); r9/r10 lesson: 512-thr blocks
// trigger a 32-VGPR reload-everything codegen, 256-thr blocks are healthy.

typedef __attribute__((ext_vector_type(8))) short bf16x8;   // MFMA A/B frag
typedef __attribute__((ext_vector_type(4))) float f32x4;    // MFMA C/D frag
typedef __attribute__((ext_vector_type(4))) short short4v;  // packed 4x bf16

#define NBLK 2048    // 2048 blocks * 4 waves * 32 tokens = 262144

__device__ __forceinline__ short f2bf(float x) {
    union { __hip_bfloat16 h; short s; } u;
    u.h = __float2bfloat16(x);      // compiler pairs into v_cvt_pk_bf16_f32
    return u.s;
}

__device__ __forceinline__ float bloom_gelu(float x) {
    // 0.5*x*(1+tanh(0.79788456*(x+0.044715*x^3))) = x*(1 - 1/(e^{2u}+1))
    // 2u*log2(e) = 2.30220842*x + 0.10294325*x^3 -> v_exp_f32 (2^x) direct
    float x2 = x * x;
    float t1 = __builtin_fmaf(0.10294325f, x2, 2.30220842f);
    float e  = __builtin_exp2f(x * t1);
    float r  = __builtin_amdgcn_rcpf(e + 1.0f);
    return x - x * r;
}

// ---- pre-pass: W1 -> bf16 linear; W2 -> bf16 with kappa-permuted columns ----
// f bits: [7:4]=t [3:2]=q [1:0]=r ; kappa = [7:5]=t>>1 [4:3]=q [2]=t&1 [1:0]=r
__global__ __launch_bounds__(256) void cvt_weights(
    const float* __restrict__ W1, const float* __restrict__ W2,
    short* __restrict__ wsb)
{
    const int i4 = (blockIdx.x * 256 + threadIdx.x) * 4;   // 0..32764, step 4
    if (i4 < 16384) {
        float4 v = *(const float4*)(W1 + i4);
        short4v o;
        o[0]=f2bf(v.x); o[1]=f2bf(v.y); o[2]=f2bf(v.z); o[3]=f2bf(v.w);
        *(short4v*)(wsb + i4) = o;
    } else {
        const int rel = i4 - 16384;
        const int d = rel >> 8, f = rel & 255;       // 4 consecutive f share t,q
        const int t = f >> 4, qq = (f >> 2) & 3;
        const int k4 = ((t >> 1) << 5) | (qq << 3) | ((t & 1) << 2);
        float4 v = *(const float4*)(W2 + rel);
        short4v o;
        o[0]=f2bf(v.x); o[1]=f2bf(v.y); o[2]=f2bf(v.z); o[3]=f2bf(v.w);
        *(short4v*)(wsb + 16384 + (d << 8) + k4) = o;
    }
}

template<bool PRE>
__global__ __launch_bounds__(256, 2) void bloom_mlp(
    const float* __restrict__ X,  const float* __restrict__ R,
    const float* __restrict__ W1, const float* __restrict__ b1,
    const float* __restrict__ W2, const float* __restrict__ b2,
    const short* __restrict__ Wb, float* __restrict__ out)
{
    const int tid  = threadIdx.x;
    const int wid  = tid >> 6;      // wave 0..3 (independent)
    const int lane = tid & 63;
    const int q    = lane >> 4;     // 0..3
    const int c    = lane & 15;     // 0..15
    const int tok0 = (blockIdx.x * 4 + wid) << 5;   // 32 tokens per wave

    // ---- X fragments for both 16-token groups (all 16 float4 issued up front) ----
    float4 xr[2][4];
#pragma unroll
    for (int m = 0; m < 2; ++m) {
        const float* p = X + (size_t)(tok0 + 16*m + c) * 64 + q*8;
        xr[m][0] = *(const float4*)(p);
        xr[m][1] = *(const float4*)(p + 4);
        xr[m][2] = *(const float4*)(p + 32);
        xr[m][3] = *(const float4*)(p + 36);
    }
    bf16x8 a1[2][2];
#pragma unroll
    for (int m = 0; m < 2; ++m)
#pragma unroll
        for (int kb = 0; kb < 2; ++kb) {
            const float4 lo = xr[m][2*kb], hi = xr[m][2*kb+1];
            bf16x8 f;
            f[0]=f2bf(lo.x); f[1]=f2bf(lo.y); f[2]=f2bf(lo.z); f[3]=f2bf(lo.w);
            f[4]=f2bf(hi.x); f[5]=f2bf(hi.y); f[6]=f2bf(hi.z); f[7]=f2bf(hi.w);
            a1[m][kb] = f;
        }

    // ---- GEMM1 + GELU, G stays in registers (gfr[m][kb] = t-pair 2kb,2kb+1) ----
    bf16x8 gfr[2][8];
#pragma unroll
    for (int t = 0; t < 16; ++t) {
        bf16x8 w1a, w1b;   // lane holds W1[16t+c][kb*32+q*8..+7]
        if constexpr (PRE) {
            w1a = *(const bf16x8*)&Wb[(16*t + c) * 64 + q*8];
            w1b = *(const bf16x8*)&Wb[(16*t + c) * 64 + 32 + q*8];
        } else {
            const float* p = W1 + (size_t)(16*t + c) * 64 + q*8;
            float4 lo = *(const float4*)p, hi = *(const float4*)(p + 4);
            bf16x8 f;
            f[0]=f2bf(lo.x); f[1]=f2bf(lo.y); f[2]=f2bf(lo.z); f[3]=f2bf(lo.w);
            f[4]=f2bf(hi.x); f[5]=f2bf(hi.y); f[6]=f2bf(hi.z); f[7]=f2bf(hi.w);
            w1a = f;
            lo = *(const float4*)(p + 32); hi = *(const float4*)(p + 36);
            f[0]=f2bf(lo.x); f[1]=f2bf(lo.y); f[2]=f2bf(lo.z); f[3]=f2bf(lo.w);
            f[4]=f2bf(hi.x); f[5]=f2bf(hi.y); f[6]=f2bf(hi.z); f[7]=f2bf(hi.w);
            w1b = f;
        }
        const float4 b1v = *(const float4*)(b1 + 16*t + 4*q);
#pragma unroll
        for (int m = 0; m < 2; ++m) {
            f32x4 acc = {0.f, 0.f, 0.f, 0.f};
            acc = __builtin_amdgcn_mfma_f32_16x16x32_bf16(w1a, a1[m][0], acc, 0, 0, 0);
            acc = __builtin_amdgcn_mfma_f32_16x16x32_bf16(w1b, a1[m][1], acc, 0, 0, 0);
            // D[f=16t+4q+r][token=c] -> gelu -> kappa slot: gfr[m][t>>1][(t&1)*4+r]
#pragma unroll
            for (int r = 0; r < 4; ++r)
                gfr[m][t >> 1][((t & 1) << 2) + r] = f2bf(bloom_gelu(acc[r] + b1v[r]));
        }
    }

    // ---- GEMM2 over kappa-permuted W2: no LDS, no barrier, pure registers ----
    f32x4 acc2[2][4] = {{{0,0,0,0},{0,0,0,0},{0,0,0,0},{0,0,0,0}},
                        {{0,0,0,0},{0,0,0,0},{0,0,0,0},{0,0,0,0}}};
#pragma unroll
    for (int kb = 0; kb < 8; ++kb) {
        bf16x8 w2f[4];     // lane holds W2k[16dt+c][32kb+q*8..+7]
#pragma unroll
        for (int dt = 0; dt < 4; ++dt) {
            if constexpr (PRE) {
                w2f[dt] = *(const bf16x8*)&Wb[16384 + (16*dt + c) * 256 + kb*32 + q*8];
            } else {
                // inline kappa: elems 0-3 <- f=32kb+4q..+3, elems 4-7 <- f=32kb+16+4q..+3
                const float* p = W2 + (size_t)(16*dt + c) * 256 + kb*32 + 4*q;
                float4 lo = *(const float4*)p, hi = *(const float4*)(p + 16);
                bf16x8 f;
                f[0]=f2bf(lo.x); f[1]=f2bf(lo.y); f[2]=f2bf(lo.z); f[3]=f2bf(lo.w);
                f[4]=f2bf(hi.x); f[5]=f2bf(hi.y); f[6]=f2bf(hi.z); f[7]=f2bf(hi.w);
                w2f[dt] = f;
            }
        }
#pragma unroll
        for (int dt = 0; dt < 4; ++dt)
#pragma unroll
            for (int m = 0; m < 2; ++m)
                acc2[m][dt] = __builtin_amdgcn_mfma_f32_16x16x32_bf16(
                    w2f[dt], gfr[m][kb], acc2[m][dt], 0, 0, 0);
    }

    // ---- epilogue: D[d=16dt+4q+r][token=c]; float4 per (m,dt) ----
#pragma unroll
    for (int m = 0; m < 2; ++m)
#pragma unroll
        for (int dt = 0; dt < 4; ++dt) {
            const size_t off = (size_t)(tok0 + 16*m + c) * 64 + 16*dt + 4*q;
            const float4 r4  = *(const float4*)(R + off);
            const float4 b2v = *(const float4*)(b2 + 16*dt + 4*q);
            float4 o;
            o.x = acc2[m][dt][0] + b2v.x + r4.x;
            o.y = acc2[m][dt][1] + b2v.y + r4.y;
            o.z = acc2[m][dt][2] + b2v.z + r4.z;
            o.w = acc2[m][dt][3] + b2v.w + r4.w;
            *(float4*)(out + off) = o;
        }
}

extern "C" void kernel_launch(void* const* d_in, const int* in_sizes, int n_in,
                              void* d_out, int out_size, void* d_ws, size_t ws_size,
                              hipStream_t stream) {
    const float* X  = (const float*)d_in[0];
    const float* R  = (const float*)d_in[1];
    const float* W1 = (const float*)d_in[2];
    const float* b1 = (const float*)d_in[3];
    const float* W2 = (const float*)d_in[4];
    const float* b2 = (const float*)d_in[5];
    float* out = (float*)d_out;
    (void)in_sizes; (void)n_in; (void)out_size;

    if (ws_size >= 65536) {
        short* wsb = (short*)d_ws;
        cvt_weights<<<32, 256, 0, stream>>>(W1, W2, wsb);
        bloom_mlp<true><<<NBLK, 256, 0, stream>>>(X, R, W1, b1, W2, b2, wsb, out);
    } else {
        bloom_mlp<false><<<NBLK, 256, 0, stream>>>(X, R, W1, b1, W2, b2, nullptr, out);
    }
}

// Round 13
// 82.153 us; speedup vs baseline: 1.4963x; 1.1213x over previous
//
#include <hip/hip_runtime.h>
#include <hip/hip_bf16.h>

// Bloom MLP fused: h=X@W1^T+b1; g=gelu_tanh(h); out=g@W2^T+b2+residual
// X:[262144,64] f32, W1:[256,64], W2:[64,256], out:[262144,64] f32.
//
// Round 13 = round 12 with the staging-stride bug fixed (j*4096 -> j*1024:
// Xb is 2048 floats, 1024 staged per issue-round; r12 wrote OOB LDS and
// left rows 16-31 unstaged -> absmax 1.8e6).
//  - 32-token tiles: Gs[32][264] 16.9KB + Xb 8KB = 25.9KB LDS.
//  - X staged via global_load_lds (T21: inverse-swizzled source slot, same
//    XOR on read), issued one phase ahead -> zero-VGPR prefetch.
//  - R hoisted to tile start; GEMM2 in 2 chains; mid barrier non-draining
//    (lgkmcnt only), end barrier __syncthreads (drains vmcnt: staged X is
//    cross-wave-consumed).
//  - 256-thr blocks, (256,4): r5/r9/r10 lesson (tight bounds => reload/spill).
// grid 2048 x TILES=4 x 32 tokens.

typedef __attribute__((ext_vector_type(8))) short bf16x8;   // MFMA A/B frag
typedef __attribute__((ext_vector_type(4))) float f32x4;    // MFMA C/D frag
typedef __attribute__((ext_vector_type(4))) short short4v;  // packed 4x bf16

#define NBLK  2048
#define TILES 4      // 2048 * 4 * 32 = 262144 tokens

__device__ __forceinline__ short f2bf(float x) {
    union { __hip_bfloat16 h; short s; } u;
    u.h = __float2bfloat16(x);      // compiler pairs into v_cvt_pk_bf16_f32
    return u.s;
}

__device__ __forceinline__ float bloom_gelu(float x) {
    // 0.5*x*(1+tanh(0.79788456*(x+0.044715*x^3))) = x*(1 - 1/(e^{2u}+1))
    // 2u*log2(e) = 2.30220842*x + 0.10294325*x^3 -> v_exp_f32 (2^x) direct
    float x2 = x * x;
    float t1 = __builtin_fmaf(0.10294325f, x2, 2.30220842f);
    float e  = __builtin_exp2f(x * t1);
    float r  = __builtin_amdgcn_rcpf(e + 1.0f);
    return x - x * r;
}

// async global->LDS, 16B per lane; dest must be lane-linear (base+lane*16)
__device__ __forceinline__ void gload_lds16(const float* src, float* dst) {
    __builtin_amdgcn_global_load_lds(
        (const __attribute__((address_space(1))) void*)src,
        (__attribute__((address_space(3))) void*)dst, 16, 0, 0);
}

// non-draining barrier: LDS visibility only, vmem stays in flight
__device__ __forceinline__ void bar_lgkm() {
    asm volatile("s_waitcnt lgkmcnt(0)" ::: "memory");
    __builtin_amdgcn_s_barrier();
    asm volatile("" ::: "memory");
}

// ---- pre-pass: convert W1 (16384 f32) then W2 (16384 f32) to bf16 in ws ----
__global__ __launch_bounds__(256) void cvt_weights(
    const float* __restrict__ W1, const float* __restrict__ W2,
    short* __restrict__ wsb)
{
    const int i4 = (blockIdx.x * 256 + threadIdx.x) * 4;   // 0..32764, step 4
    const float* src = (i4 < 16384) ? (W1 + i4) : (W2 + (i4 - 16384));
    float4 v = *(const float4*)src;
    short4v o;
    o[0] = f2bf(v.x); o[1] = f2bf(v.y); o[2] = f2bf(v.z); o[3] = f2bf(v.w);
    *(short4v*)(wsb + i4) = o;
}

template<bool PRE>
__global__ __launch_bounds__(256, 4) void bloom_mlp(
    const float* __restrict__ X,  const float* __restrict__ R,
    const float* __restrict__ W1, const float* __restrict__ b1,
    const float* __restrict__ W2, const float* __restrict__ b2,
    const short* __restrict__ Wb, float* __restrict__ out)
{
    // Gs: G[token][f] bf16, 32 tokens, row stride 264 (528B).
    // Xb: staged X tile, 32 tok x 64 f32; 16B slots XOR-swizzled by row&15.
    __shared__ __align__(16) short Gs[32][264];   // 16896 B
    __shared__ __align__(16) float Xb[2048];      //  8192 B

    const int tid  = threadIdx.x;
    const int wid  = tid >> 6;      // wave 0..3
    const int lane = tid & 63;
    const int q    = lane >> 4;     // 0..3
    const int c    = lane & 15;     // 0..15
    const int f0   = wid << 6;      // GEMM1 f-slice base (64 f per wave)
    const int row0 = blockIdx.x << 7;   // 128 tokens per block

    // stage one 32-token X tile: 2048 floats, 2 issues/thread of 16B.
    // dest didx = j*1024 + tid*4 (lane-linear); row = didx>>6 (64 f/row);
    // source 16B slot = destslot ^ (row&15)  (T21: inverse-swz source).
    auto stage_x = [&](int rowbase) {
#pragma unroll
        for (int j = 0; j < 2; ++j) {
            const int didx = j * 1024 + tid * 4;           // 0..2044
            const int row  = didx >> 6;                    // 0..31
            const int hs   = ((didx >> 2) & 15) ^ (row & 15);
            gload_lds16(X + (size_t)(rowbase + row) * 64 + (hs << 2), &Xb[didx]);
        }
    };

    stage_x(row0);    // tile 0 in flight immediately (overlaps weight load)

    // ---- weight fragments, register-resident across tiles ----
    bf16x8 w1f[4][2];   // GEMM1 A-op: lane holds W1[f0+16t+c][kb*32+q*8..+7]
    bf16x8 w2f[8];      // GEMM2 A-op: lane holds W2[16wid+c][kb*32+q*8..+7]
    if constexpr (PRE) {
        const short* W1b = Wb;
        const short* W2b = Wb + 16384;
#pragma unroll
        for (int t = 0; t < 4; ++t)
#pragma unroll
            for (int kb = 0; kb < 2; ++kb)
                w1f[t][kb] = *(const bf16x8*)&W1b[(f0 + 16*t + c) * 64 + kb*32 + q*8];
#pragma unroll
        for (int kb = 0; kb < 8; ++kb)
            w2f[kb] = *(const bf16x8*)&W2b[(16*wid + c) * 256 + kb*32 + q*8];
    } else {
#pragma unroll
        for (int t = 0; t < 4; ++t)
#pragma unroll
            for (int kb = 0; kb < 2; ++kb) {
                const float* p = W1 + (size_t)(f0 + 16*t + c) * 64 + kb*32 + q*8;
                float4 lo = *(const float4*)p, hi = *(const float4*)(p + 4);
                bf16x8 f;
                f[0]=f2bf(lo.x); f[1]=f2bf(lo.y); f[2]=f2bf(lo.z); f[3]=f2bf(lo.w);
                f[4]=f2bf(hi.x); f[5]=f2bf(hi.y); f[6]=f2bf(hi.z); f[7]=f2bf(hi.w);
                w1f[t][kb] = f;
            }
#pragma unroll
        for (int kb = 0; kb < 8; ++kb) {
            const float* p = W2 + (size_t)(16*wid + c) * 256 + kb*32 + q*8;
            float4 lo = *(const float4*)p, hi = *(const float4*)(p + 4);
            bf16x8 f;
            f[0]=f2bf(lo.x); f[1]=f2bf(lo.y); f[2]=f2bf(lo.z); f[3]=f2bf(lo.w);
            f[4]=f2bf(hi.x); f[5]=f2bf(hi.y); f[6]=f2bf(hi.z); f[7]=f2bf(hi.w);
            w2f[kb] = f;
        }
    }

    const float4 b2q = *(const float4*)(b2 + 16*wid + 4*q);

    __syncthreads();   // X tile 0 staged (drains own vmcnt) + all waves synced

    for (int it = 0; it < TILES; ++it) {
        const int rowT = row0 + (it << 5);

        // ---- R hoisted: issued now, consumed after GEMM2 (latency hidden) ----
        float4 r4h[2];
#pragma unroll
        for (int m = 0; m < 2; ++m)
            r4h[m] = *(const float4*)(R + (size_t)(rowT + 16*m + c) * 64 + 16*wid + 4*q);

        // ---- GEMM1 + GELU -> Gs, X from swizzled Xb ----
#pragma unroll
        for (int m = 0; m < 2; ++m) {
            const int xrow = (16*m + c) << 6;
            const int sw   = c;                 // (16m+c)&15 == c
            bf16x8 a1[2];
#pragma unroll
            for (int kb = 0; kb < 2; ++kb) {
                const int h0 = 8*kb + 2*q;      // wanted 16B slots
                const float4 lo = *(const float4*)&Xb[xrow + (((h0    ) ^ sw) << 2)];
                const float4 hi = *(const float4*)&Xb[xrow + (((h0 + 1) ^ sw) << 2)];
                bf16x8 f;
                f[0]=f2bf(lo.x); f[1]=f2bf(lo.y); f[2]=f2bf(lo.z); f[3]=f2bf(lo.w);
                f[4]=f2bf(hi.x); f[5]=f2bf(hi.y); f[6]=f2bf(hi.z); f[7]=f2bf(hi.w);
                a1[kb] = f;
            }
            // D[f_local=4q+r][token=c] per f-tile t
#pragma unroll
            for (int t = 0; t < 4; ++t) {
                const float4 b1q = *(const float4*)(b1 + f0 + 16*t + 4*q);
                f32x4 acc = {0.f, 0.f, 0.f, 0.f};
                acc = __builtin_amdgcn_mfma_f32_16x16x32_bf16(w1f[t][0], a1[0], acc, 0, 0, 0);
                acc = __builtin_amdgcn_mfma_f32_16x16x32_bf16(w1f[t][1], a1[1], acc, 0, 0, 0);
                short4v g;
#pragma unroll
                for (int r = 0; r < 4; ++r)
                    g[r] = f2bf(bloom_gelu(acc[r] + b1q[r]));
                *(short4v*)&Gs[16*m + c][f0 + 16*t + 4*q] = g;   // 8B packed
            }
        }

        bar_lgkm();   // Gs ready; Xb fully consumed; vmem stays in flight

        // next X tile issued NOW -> lands during GEMM2 + epilogue
        if (it + 1 < TILES) stage_x(rowT + 32);

        // ---- GEMM2: wave owns d-tile [16wid,16wid+16) over K=256 ----
        // D[d_local=4q+r][token=c]; 2 chains (kb 0-3 / 4-7)
        f32x4 aA[2] = {{0.f,0.f,0.f,0.f},{0.f,0.f,0.f,0.f}};
        f32x4 aB[2] = {{0.f,0.f,0.f,0.f},{0.f,0.f,0.f,0.f}};
#pragma unroll
        for (int kb = 0; kb < 4; ++kb)
#pragma unroll
            for (int m = 0; m < 2; ++m) {
                bf16x8 ga = *(const bf16x8*)&Gs[16*m + c][kb*32 + q*8];
                aA[m] = __builtin_amdgcn_mfma_f32_16x16x32_bf16(w2f[kb], ga, aA[m], 0, 0, 0);
            }
#pragma unroll
        for (int kb = 4; kb < 8; ++kb)
#pragma unroll
            for (int m = 0; m < 2; ++m) {
                bf16x8 ga = *(const bf16x8*)&Gs[16*m + c][kb*32 + q*8];
                aB[m] = __builtin_amdgcn_mfma_f32_16x16x32_bf16(w2f[kb], ga, aB[m], 0, 0, 0);
            }

        // ---- epilogue: float4 out[rowT+16m+c][16wid+4q..+3] (R pre-loaded) ----
#pragma unroll
        for (int m = 0; m < 2; ++m) {
            const size_t off = (size_t)(rowT + 16*m + c) * 64 + 16*wid + 4*q;
            float4 o;
            o.x = aA[m][0] + aB[m][0] + b2q.x + r4h[m].x;
            o.y = aA[m][1] + aB[m][1] + b2q.y + r4h[m].y;
            o.z = aA[m][2] + aB[m][2] + b2q.z + r4h[m].z;
            o.w = aA[m][3] + aB[m][3] + b2q.w + r4h[m].w;
            *(float4*)(out + off) = o;
        }

        // staged X is cross-wave-consumed: __syncthreads drains own vmcnt
        // before the barrier -> writes visible; also protects Gs WAR.
        if (it + 1 < TILES) __syncthreads();
    }
}

extern "C" void kernel_launch(void* const* d_in, const int* in_sizes, int n_in,
                              void* d_out, int out_size, void* d_ws, size_t ws_size,
                              hipStream_t stream) {
    const float* X  = (const float*)d_in[0];
    const float* R  = (const float*)d_in[1];
    const float* W1 = (const float*)d_in[2];
    const float* b1 = (const float*)d_in[3];
    const float* W2 = (const float*)d_in[4];
    const float* b2 = (const float*)d_in[5];
    float* out = (float*)d_out;
    (void)in_sizes; (void)n_in; (void)out_size;

    if (ws_size >= 65536) {
        short* wsb = (short*)d_ws;
        cvt_weights<<<32, 256, 0, stream>>>(W1, W2, wsb);
        bloom_mlp<true><<<NBLK, 256, 0, stream>>>(X, R, W1, b1, W2, b2, wsb, out);
    } else {
        bloom_mlp<false><<<NBLK, 256, 0, stream>>>(X, R, W1, b1, W2, b2, nullptr, out);
    }
}

// Round 14
// 65.702 us; speedup vs baseline: 1.8709x; 1.2504x over previous
//
#include <hip/hip_runtime.h>
#include <hip/hip_bf16.h>

// Bloom MLP fused: h=X@W1^T+b1; g=gelu_tanh(h); out=g@W2^T+b2+residual
// X:[262144,64] f32, W1:[256,64], W2:[64,256], out:[262144,64] f32.
//
// Round 14 = round 13 with the L3-locality regression fixed + deeper prefetch:
//  - R load moved back to post-bar_lgkm (r8 position). r13 hoisted R to tile
//    start and warm FETCH blew up 66->145MB (L3-capacity-edge thrash), the
//    entire +12us regression. R-read stays temporally near the out-write.
//  - Xb double-buffered [2][2048]: stage(it+1) issued at TOP of tile it ->
//    ~2 phases of latency cover; end-of-tile __syncthreads drain is ~free.
//    WAR distance on each buffer = 2 tiles (>=4 barriers).
//  - b1 hoisted to prologue (loop-invariant per wave).
//  - Everything else proven: 32-token tiles, Gs[32][264], T21 source-swizzled
//    global_load_lds staging, 2-chain GEMM2, PRE bf16 weights, (256,4).
// grid 2048 x TILES=4 x 32 tokens. LDS 33.3KB.

typedef __attribute__((ext_vector_type(8))) short bf16x8;   // MFMA A/B frag
typedef __attribute__((ext_vector_type(4))) float f32x4;    // MFMA C/D frag
typedef __attribute__((ext_vector_type(4))) short short4v;  // packed 4x bf16

#define NBLK  2048
#define TILES 4      // 2048 * 4 * 32 = 262144 tokens

__device__ __forceinline__ short f2bf(float x) {
    union { __hip_bfloat16 h; short s; } u;
    u.h = __float2bfloat16(x);      // compiler pairs into v_cvt_pk_bf16_f32
    return u.s;
}

__device__ __forceinline__ float bloom_gelu(float x) {
    // 0.5*x*(1+tanh(0.79788456*(x+0.044715*x^3))) = x*(1 - 1/(e^{2u}+1))
    // 2u*log2(e) = 2.30220842*x + 0.10294325*x^3 -> v_exp_f32 (2^x) direct
    float x2 = x * x;
    float t1 = __builtin_fmaf(0.10294325f, x2, 2.30220842f);
    float e  = __builtin_exp2f(x * t1);
    float r  = __builtin_amdgcn_rcpf(e + 1.0f);
    return x - x * r;
}

// async global->LDS, 16B per lane; dest must be lane-linear (base+lane*16)
__device__ __forceinline__ void gload_lds16(const float* src, float* dst) {
    __builtin_amdgcn_global_load_lds(
        (const __attribute__((address_space(1))) void*)src,
        (__attribute__((address_space(3))) void*)dst, 16, 0, 0);
}

// non-draining barrier: LDS visibility only, vmem stays in flight
__device__ __forceinline__ void bar_lgkm() {
    asm volatile("s_waitcnt lgkmcnt(0)" ::: "memory");
    __builtin_amdgcn_s_barrier();
    asm volatile("" ::: "memory");
}

// ---- pre-pass: convert W1 (16384 f32) then W2 (16384 f32) to bf16 in ws ----
__global__ __launch_bounds__(256) void cvt_weights(
    const float* __restrict__ W1, const float* __restrict__ W2,
    short* __restrict__ wsb)
{
    const int i4 = (blockIdx.x * 256 + threadIdx.x) * 4;   // 0..32764, step 4
    const float* src = (i4 < 16384) ? (W1 + i4) : (W2 + (i4 - 16384));
    float4 v = *(const float4*)src;
    short4v o;
    o[0] = f2bf(v.x); o[1] = f2bf(v.y); o[2] = f2bf(v.z); o[3] = f2bf(v.w);
    *(short4v*)(wsb + i4) = o;
}

template<bool PRE>
__global__ __launch_bounds__(256, 4) void bloom_mlp(
    const float* __restrict__ X,  const float* __restrict__ R,
    const float* __restrict__ W1, const float* __restrict__ b1,
    const float* __restrict__ W2, const float* __restrict__ b2,
    const short* __restrict__ Wb, float* __restrict__ out)
{
    // Gs: G[token][f] bf16, 32 tokens, row stride 264 (528B).
    // Xb: double-buffered staged X tile, each 32 tok x 64 f32;
    //     16B slots XOR-swizzled by row&15 (T21: swizzle source + read).
    __shared__ __align__(16) short Gs[32][264];    // 16896 B
    __shared__ __align__(16) float Xb[2][2048];    // 16384 B

    const int tid  = threadIdx.x;
    const int wid  = tid >> 6;      // wave 0..3
    const int lane = tid & 63;
    const int q    = lane >> 4;     // 0..3
    const int c    = lane & 15;     // 0..15
    const int f0   = wid << 6;      // GEMM1 f-slice base (64 f per wave)
    const int row0 = blockIdx.x << 7;   // 128 tokens per block

    // stage one 32-token X tile: 2048 floats, 2 x 16B per thread.
    // dest didx = j*1024 + tid*4 (lane-linear); row = didx>>6;
    // source 16B slot = destslot ^ (row&15).
    auto stage_x = [&](float* xb, int rowbase) {
#pragma unroll
        for (int j = 0; j < 2; ++j) {
            const int didx = j * 1024 + tid * 4;           // 0..2044
            const int row  = didx >> 6;                    // 0..31
            const int hs   = ((didx >> 2) & 15) ^ (row & 15);
            gload_lds16(X + (size_t)(rowbase + row) * 64 + (hs << 2), xb + didx);
        }
    };

    stage_x(Xb[0], row0);   // tile 0 in flight immediately (overlaps weights)

    // ---- weight fragments + biases, register-resident across tiles ----
    bf16x8 w1f[4][2];   // GEMM1 A-op: lane holds W1[f0+16t+c][kb*32+q*8..+7]
    bf16x8 w2f[8];      // GEMM2 A-op: lane holds W2[16wid+c][kb*32+q*8..+7]
    if constexpr (PRE) {
        const short* W1b = Wb;
        const short* W2b = Wb + 16384;
#pragma unroll
        for (int t = 0; t < 4; ++t)
#pragma unroll
            for (int kb = 0; kb < 2; ++kb)
                w1f[t][kb] = *(const bf16x8*)&W1b[(f0 + 16*t + c) * 64 + kb*32 + q*8];
#pragma unroll
        for (int kb = 0; kb < 8; ++kb)
            w2f[kb] = *(const bf16x8*)&W2b[(16*wid + c) * 256 + kb*32 + q*8];
    } else {
#pragma unroll
        for (int t = 0; t < 4; ++t)
#pragma unroll
            for (int kb = 0; kb < 2; ++kb) {
                const float* p = W1 + (size_t)(f0 + 16*t + c) * 64 + kb*32 + q*8;
                float4 lo = *(const float4*)p, hi = *(const float4*)(p + 4);
                bf16x8 f;
                f[0]=f2bf(lo.x); f[1]=f2bf(lo.y); f[2]=f2bf(lo.z); f[3]=f2bf(lo.w);
                f[4]=f2bf(hi.x); f[5]=f2bf(hi.y); f[6]=f2bf(hi.z); f[7]=f2bf(hi.w);
                w1f[t][kb] = f;
            }
#pragma unroll
        for (int kb = 0; kb < 8; ++kb) {
            const float* p = W2 + (size_t)(16*wid + c) * 256 + kb*32 + q*8;
            float4 lo = *(const float4*)p, hi = *(const float4*)(p + 4);
            bf16x8 f;
            f[0]=f2bf(lo.x); f[1]=f2bf(lo.y); f[2]=f2bf(lo.z); f[3]=f2bf(lo.w);
            f[4]=f2bf(hi.x); f[5]=f2bf(hi.y); f[6]=f2bf(hi.z); f[7]=f2bf(hi.w);
            w2f[kb] = f;
        }
    }

    float4 b1q[4];      // wave's b1 slice (loop-invariant)
#pragma unroll
    for (int t = 0; t < 4; ++t)
        b1q[t] = *(const float4*)(b1 + f0 + 16*t + 4*q);
    const float4 b2q = *(const float4*)(b2 + 16*wid + 4*q);

    __syncthreads();   // X tile 0 staged (drains own vmcnt) + all waves synced

    for (int it = 0; it < TILES; ++it) {
        const int rowT = row0 + (it << 5);
        const int cur  = it & 1;

        // ---- next tile staged FIRST: ~2 phases of latency cover ----
        if (it + 1 < TILES) stage_x(Xb[cur ^ 1], rowT + 32);

        // ---- GEMM1 + GELU -> Gs, X from swizzled Xb[cur] ----
#pragma unroll
        for (int m = 0; m < 2; ++m) {
            const int xrow = (16*m + c) << 6;
            const int sw   = c;                 // (16m+c)&15 == c
            bf16x8 a1[2];
#pragma unroll
            for (int kb = 0; kb < 2; ++kb) {
                const int h0 = 8*kb + 2*q;      // wanted 16B slots
                const float4 lo = *(const float4*)&Xb[cur][xrow + (((h0    ) ^ sw) << 2)];
                const float4 hi = *(const float4*)&Xb[cur][xrow + (((h0 + 1) ^ sw) << 2)];
                bf16x8 f;
                f[0]=f2bf(lo.x); f[1]=f2bf(lo.y); f[2]=f2bf(lo.z); f[3]=f2bf(lo.w);
                f[4]=f2bf(hi.x); f[5]=f2bf(hi.y); f[6]=f2bf(hi.z); f[7]=f2bf(hi.w);
                a1[kb] = f;
            }
            // D[f_local=4q+r][token=c] per f-tile t
#pragma unroll
            for (int t = 0; t < 4; ++t) {
                f32x4 acc = {0.f, 0.f, 0.f, 0.f};
                acc = __builtin_amdgcn_mfma_f32_16x16x32_bf16(w1f[t][0], a1[0], acc, 0, 0, 0);
                acc = __builtin_amdgcn_mfma_f32_16x16x32_bf16(w1f[t][1], a1[1], acc, 0, 0, 0);
                short4v g;
#pragma unroll
                for (int r = 0; r < 4; ++r)
                    g[r] = f2bf(bloom_gelu(acc[r] + b1q[t][r]));
                *(short4v*)&Gs[16*m + c][f0 + 16*t + 4*q] = g;   // 8B packed
            }
        }

        bar_lgkm();   // Gs ready; Xb[cur] consumed; vmem stays in flight

        // ---- R issued here (r8 position): hides under GEMM2, stays
        //      temporally near the out-write of the same lines (L3 regime) ----
        float4 r4h[2];
#pragma unroll
        for (int m = 0; m < 2; ++m)
            r4h[m] = *(const float4*)(R + (size_t)(rowT + 16*m + c) * 64 + 16*wid + 4*q);

        // ---- GEMM2: wave owns d-tile [16wid,16wid+16) over K=256 ----
        // D[d_local=4q+r][token=c]; 2 chains (kb 0-3 / 4-7)
        f32x4 aA[2] = {{0.f,0.f,0.f,0.f},{0.f,0.f,0.f,0.f}};
        f32x4 aB[2] = {{0.f,0.f,0.f,0.f},{0.f,0.f,0.f,0.f}};
#pragma unroll
        for (int kb = 0; kb < 4; ++kb)
#pragma unroll
            for (int m = 0; m < 2; ++m) {
                bf16x8 ga = *(const bf16x8*)&Gs[16*m + c][kb*32 + q*8];
                aA[m] = __builtin_amdgcn_mfma_f32_16x16x32_bf16(w2f[kb], ga, aA[m], 0, 0, 0);
            }
#pragma unroll
        for (int kb = 4; kb < 8; ++kb)
#pragma unroll
            for (int m = 0; m < 2; ++m) {
                bf16x8 ga = *(const bf16x8*)&Gs[16*m + c][kb*32 + q*8];
                aB[m] = __builtin_amdgcn_mfma_f32_16x16x32_bf16(w2f[kb], ga, aB[m], 0, 0, 0);
            }

        // ---- epilogue: float4 out[rowT+16m+c][16wid+4q..+3] ----
#pragma unroll
        for (int m = 0; m < 2; ++m) {
            const size_t off = (size_t)(rowT + 16*m + c) * 64 + 16*wid + 4*q;
            float4 o;
            o.x = aA[m][0] + aB[m][0] + b2q.x + r4h[m].x;
            o.y = aA[m][1] + aB[m][1] + b2q.y + r4h[m].y;
            o.z = aA[m][2] + aB[m][2] + b2q.z + r4h[m].z;
            o.w = aA[m][3] + aB[m][3] + b2q.w + r4h[m].w;
            *(float4*)(out + off) = o;
        }

        // staged X is cross-wave-consumed: __syncthreads drains own vmcnt
        // (stage loads issued ~2 phases ago -> drain ~free); also Gs WAR.
        if (it + 1 < TILES) __syncthreads();
    }
}

extern "C" void kernel_launch(void* const* d_in, const int* in_sizes, int n_in,
                              void* d_out, int out_size, void* d_ws, size_t ws_size,
                              hipStream_t stream) {
    const float* X  = (const float*)d_in[0];
    const float* R  = (const float*)d_in[1];
    const float* W1 = (const float*)d_in[2];
    const float* b1 = (const float*)d_in[3];
    const float* W2 = (const float*)d_in[4];
    const float* b2 = (const float*)d_in[5];
    float* out = (float*)d_out;
    (void)in_sizes; (void)n_in; (void)out_size;

    if (ws_size >= 65536) {
        short* wsb = (short*)d_ws;
        cvt_weights<<<32, 256, 0, stream>>>(W1, W2, wsb);
        bloom_mlp<true><<<NBLK, 256, 0, stream>>>(X, R, W1, b1, W2, b2, wsb, out);
    } else {
        bloom_mlp<false><<<NBLK, 256, 0, stream>>>(X, R, W1, b1, W2, b2, nullptr, out);
    }
}

// Round 15
// 65.121 us; speedup vs baseline: 1.8876x; 1.0089x over previous
//
#include <hip/hip_runtime.h>
#include <hip/hip_bf16.h>

// Bloom MLP fused: h=X@W1^T+b1; g=gelu_tanh(h); out=g@W2^T+b2+residual
// X:[262144,64] f32, W1:[256,64], W2:[64,256], out:[262144,64] f32.
//
// Round 15: zero-barrier kappa structure (r11) with both failure causes fixed.
//  - kappa trick (r11-proven): GEMM1 swapped-ops leaves lane(c,q) with
//    G[token=c][f=16t+4q+r]; W2 stored column-permuted by
//    kappa(f)=[t>>1|q|t&1|r] so GEMM2's A-fragment IS the GEMM1 output
//    (register re-labeling). G never touches LDS; no barriers in the loop.
//  - weights in LDS (64KB/block), staged once from pre-converted ws via
//    global_load_lds; XOR swizzle (slot^=row&7) baked into the ws image so
//    staging is linear (T21) and both W1/W2 b128 reads are at the inherent
//    bank minimum. ONE __syncthreads total.
//  - launch_bounds(256,1): permissive cap -> no spill-for-occupancy
//    (r5/r9/r10: forced occupancy strangles; r11: heuristic demoted to 60).
//  - X for both tiles issued in prologue (fly across weight staging);
//    R stays in epilogue next to the out-write (r13/r14 L3 lesson).
// 1024 blocks x 4 waves x 2 tiles x 32 tokens.

typedef __attribute__((ext_vector_type(8))) short bf16x8;   // MFMA A/B frag
typedef __attribute__((ext_vector_type(4))) float f32x4;    // MFMA C/D frag
typedef __attribute__((ext_vector_type(4))) short short4v;  // packed 4x bf16

#define NBLK  1024
#define TILES 2      // 1024 * 4 waves * 2 * 32 = 262144 tokens

__device__ __forceinline__ short f2bf(float x) {
    union { __hip_bfloat16 h; short s; } u;
    u.h = __float2bfloat16(x);      // compiler pairs into v_cvt_pk_bf16_f32
    return u.s;
}

__device__ __forceinline__ float bloom_gelu(float x) {
    // 0.5*x*(1+tanh(0.79788456*(x+0.044715*x^3))) = x*(1 - 1/(e^{2u}+1))
    // 2u*log2(e) = 2.30220842*x + 0.10294325*x^3 -> v_exp_f32 (2^x) direct
    float x2 = x * x;
    float t1 = __builtin_fmaf(0.10294325f, x2, 2.30220842f);
    float e  = __builtin_exp2f(x * t1);
    float r  = __builtin_amdgcn_rcpf(e + 1.0f);
    return x - x * r;
}

// swizzled short-offsets into the packed weight image.
// W1 region: [256 rows][64 shorts] (8 slots of 8 shorts per row).
// W2 region: [64 rows][256 shorts] (32 slots), kappa-permuted columns.
__device__ __forceinline__ int w1_off(int row, int slot) {
    return row * 64 + ((slot ^ (row & 7)) << 3);
}
__device__ __forceinline__ int w2_off(int row, int slot) {
    return 16384 + row * 256 + ((slot ^ (row & 7)) << 3);
}

// async global->LDS, 16B per lane; dest lane-linear (base+lane*16)
__device__ __forceinline__ void gload_lds16(const void* src, void* dst) {
    __builtin_amdgcn_global_load_lds(
        (const __attribute__((address_space(1))) void*)src,
        (__attribute__((address_space(3))) void*)dst, 16, 0, 0);
}

// ---- pre-pass: build the swizzled bf16 weight image in ws ----
// f bits of W2 col: [7:4]=t [3:2]=qq [1:0]=r ; kappa=[7:5]=t>>1 [4:3]=qq [2]=t&1 [1:0]=r
__global__ __launch_bounds__(256) void cvt_weights(
    const float* __restrict__ W1, const float* __restrict__ W2,
    short* __restrict__ wsb)
{
    const int i4 = (blockIdx.x * 256 + threadIdx.x) * 4;   // 0..32764, step 4
    if (i4 < 16384) {
        const int row = i4 >> 6, col = i4 & 63;            // col%8 in {0,4}
        float4 v = *(const float4*)(W1 + i4);
        short4v o;
        o[0]=f2bf(v.x); o[1]=f2bf(v.y); o[2]=f2bf(v.z); o[3]=f2bf(v.w);
        *(short4v*)(wsb + w1_off(row, col >> 3) + (col & 7)) = o;
    } else {
        const int rel = i4 - 16384;
        const int d = rel >> 8, f = rel & 255;             // 4 f share t,qq
        const int t = f >> 4, qq = (f >> 2) & 3;
        const int k4 = ((t >> 1) << 5) | (qq << 3) | ((t & 1) << 2);
        float4 v = *(const float4*)(W2 + rel);
        short4v o;
        o[0]=f2bf(v.x); o[1]=f2bf(v.y); o[2]=f2bf(v.z); o[3]=f2bf(v.w);
        *(short4v*)(wsb + w2_off(d, k4 >> 3) + (k4 & 7)) = o;
    }
}

template<bool PRE>
__global__ __launch_bounds__(256, 1) void bloom_mlp(
    const float* __restrict__ X,  const float* __restrict__ R,
    const float* __restrict__ W1, const float* __restrict__ b1,
    const float* __restrict__ W2, const float* __restrict__ b2,
    const short* __restrict__ Wb, float* __restrict__ out)
{
    __shared__ __align__(16) short Wlds[32768];   // 64 KB swizzled weights

    const int tid  = threadIdx.x;
    const int wid  = tid >> 6;      // wave 0..3 (fully independent)
    const int lane = tid & 63;
    const int q    = lane >> 4;     // 0..3
    const int c    = lane & 15;     // 0..15
    const int tokB = blockIdx.x * (4 * TILES * 32) + wid * (TILES * 32);

    // ---- issue X for BOTH tiles now: flies across the weight staging ----
    float4 xr[TILES][2][4];
#pragma unroll
    for (int it = 0; it < TILES; ++it)
#pragma unroll
        for (int m = 0; m < 2; ++m) {
            const float* p = X + (size_t)(tokB + it*32 + 16*m + c) * 64 + q*8;
            xr[it][m][0] = *(const float4*)(p);
            xr[it][m][1] = *(const float4*)(p + 4);
            xr[it][m][2] = *(const float4*)(p + 32);
            xr[it][m][3] = *(const float4*)(p + 36);
        }

    // ---- stage weights into LDS ----
    if constexpr (PRE) {
        // ws image already bf16+swizzled: linear 64KB copy, 16x16B/thread
#pragma unroll
        for (int k = 0; k < 16; ++k) {
            const int s8 = (k * 256 + tid) * 8;            // short index
            gload_lds16(Wb + s8, &Wlds[s8]);
        }
    } else {
        // convert+swizzle from f32 globals (fallback; ws too small)
#pragma unroll
        for (int k = 0; k < 16; ++k) {
            const int i4 = (k * 256 + tid) * 4;            // W1 floats
            const int row = i4 >> 6, col = i4 & 63;
            float4 v = *(const float4*)(W1 + i4);
            short4v o;
            o[0]=f2bf(v.x); o[1]=f2bf(v.y); o[2]=f2bf(v.z); o[3]=f2bf(v.w);
            *(short4v*)&Wlds[w1_off(row, col >> 3) + (col & 7)] = o;
        }
#pragma unroll
        for (int k = 0; k < 16; ++k) {
            const int rel = (k * 256 + tid) * 4;           // W2 floats
            const int d = rel >> 8, f = rel & 255;
            const int t = f >> 4, qq = (f >> 2) & 3;
            const int k4 = ((t >> 1) << 5) | (qq << 3) | ((t & 1) << 2);
            float4 v = *(const float4*)(W2 + rel);
            short4v o;
            o[0]=f2bf(v.x); o[1]=f2bf(v.y); o[2]=f2bf(v.z); o[3]=f2bf(v.w);
            *(short4v*)&Wlds[w2_off(d, k4 >> 3) + (k4 & 7)] = o;
        }
    }

    __syncthreads();   // THE one barrier: weights staged (drains vmcnt/lgkm)

    // ================= per-tile, zero-sync pipeline =================
#pragma unroll
    for (int it = 0; it < TILES; ++it) {
        const int tok0 = tokB + it * 32;

        // X fragments (frees xr[it])
        bf16x8 a1[2][2];
#pragma unroll
        for (int m = 0; m < 2; ++m)
#pragma unroll
            for (int kb = 0; kb < 2; ++kb) {
                const float4 lo = xr[it][m][2*kb], hi = xr[it][m][2*kb+1];
                bf16x8 f;
                f[0]=f2bf(lo.x); f[1]=f2bf(lo.y); f[2]=f2bf(lo.z); f[3]=f2bf(lo.w);
                f[4]=f2bf(hi.x); f[5]=f2bf(hi.y); f[6]=f2bf(hi.z); f[7]=f2bf(hi.w);
                a1[m][kb] = f;
            }

        // ---- GEMM1 + GELU, G straight into kappa register slots ----
        bf16x8 gfr[2][8];
#pragma unroll
        for (int t = 0; t < 16; ++t) {
            const int row = 16*t + c;
            const bf16x8 w1a = *(const bf16x8*)&Wlds[w1_off(row, q)];      // k 0..31
            const bf16x8 w1b = *(const bf16x8*)&Wlds[w1_off(row, 4 + q)];  // k 32..63
            const float4 b1v = *(const float4*)(b1 + 16*t + 4*q);
#pragma unroll
            for (int m = 0; m < 2; ++m) {
                f32x4 acc = {0.f, 0.f, 0.f, 0.f};
                acc = __builtin_amdgcn_mfma_f32_16x16x32_bf16(w1a, a1[m][0], acc, 0, 0, 0);
                acc = __builtin_amdgcn_mfma_f32_16x16x32_bf16(w1b, a1[m][1], acc, 0, 0, 0);
                // D[f=16t+4q+r][token=c] -> kappa slot gfr[m][t>>1][(t&1)*4+r]
#pragma unroll
                for (int r = 0; r < 4; ++r)
                    gfr[m][t >> 1][((t & 1) << 2) + r] =
                        f2bf(bloom_gelu(acc[r] + b1v[r]));
            }
        }

        // ---- GEMM2 over kappa-permuted W2 (LDS broadcast reads) ----
        f32x4 acc2[2][4] = {{{0,0,0,0},{0,0,0,0},{0,0,0,0},{0,0,0,0}},
                            {{0,0,0,0},{0,0,0,0},{0,0,0,0},{0,0,0,0}}};
#pragma unroll
        for (int kb = 0; kb < 8; ++kb)
#pragma unroll
            for (int dt = 0; dt < 4; ++dt) {
                const bf16x8 w2f = *(const bf16x8*)&Wlds[w2_off(16*dt + c, kb*4 + q)];
#pragma unroll
                for (int m = 0; m < 2; ++m)
                    acc2[m][dt] = __builtin_amdgcn_mfma_f32_16x16x32_bf16(
                        w2f, gfr[m][kb], acc2[m][dt], 0, 0, 0);
            }

        // ---- epilogue: D[d=16dt+4q+r][token=c]; R next to out-write ----
#pragma unroll
        for (int m = 0; m < 2; ++m)
#pragma unroll
            for (int dt = 0; dt < 4; ++dt) {
                const size_t off = (size_t)(tok0 + 16*m + c) * 64 + 16*dt + 4*q;
                const float4 r4  = *(const float4*)(R + off);
                const float4 b2v = *(const float4*)(b2 + 16*dt + 4*q);
                float4 o;
                o.x = acc2[m][dt][0] + b2v.x + r4.x;
                o.y = acc2[m][dt][1] + b2v.y + r4.y;
                o.z = acc2[m][dt][2] + b2v.z + r4.z;
                o.w = acc2[m][dt][3] + b2v.w + r4.w;
                *(float4*)(out + off) = o;
            }
    }
}

extern "C" void kernel_launch(void* const* d_in, const int* in_sizes, int n_in,
                              void* d_out, int out_size, void* d_ws, size_t ws_size,
                              hipStream_t stream) {
    const float* X  = (const float*)d_in[0];
    const float* R  = (const float*)d_in[1];
    const float* W1 = (const float*)d_in[2];
    const float* b1 = (const float*)d_in[3];
    const float* W2 = (const float*)d_in[4];
    const float* b2 = (const float*)d_in[5];
    float* out = (float*)d_out;
    (void)in_sizes; (void)n_in; (void)out_size;

    if (ws_size >= 65536) {
        short* wsb = (short*)d_ws;
        cvt_weights<<<32, 256, 0, stream>>>(W1, W2, wsb);
        bloom_mlp<true><<<NBLK, 256, 0, stream>>>(X, R, W1, b1, W2, b2, wsb, out);
    } else {
        bloom_mlp<false><<<NBLK, 256, 0, stream>>>(X, R, W1, b1, W2, b2, nullptr, out);
    }
}